// Round 9
// baseline (523.833 us; speedup 1.0000x reference)
//
#include <hip/hip_runtime.h>

#define HW 3136          // 56*56
#define NPIX 25088       // 8*3136

// workspace float offsets
#define OFF_Y1   0u
#define OFF_TR   1605632u
#define OFF_WT   2007040u      // w1t (16384) + w3t (16384)
#define OFF_OUT2 6924288u
#define OFF_Y3   8529920u
#define OFF_ST   14952448u
// stats sub-offsets (floats, relative to st base). acc: [C]=sum, [C..2C)=sumsq
#define ACC1 0
#define ACCR 128
#define ACC2 160
#define ACC3 288
#define FIN1 800
#define FINR 928
#define FIN2 960
#define FIN3 1088

__device__ __forceinline__ float wave_sum(float v) {
    #pragma unroll
    for (int off = 32; off > 0; off >>= 1) v += __shfl_xor(v, off, 64);
    return v;
}

// ---- K0: transpose weights w1[64][256]->w1t[256][64], w3[256][64]->w3t[64][256]
__global__ __launch_bounds__(256) void k_wt(const float* __restrict__ w1,
        const float* __restrict__ w3, float* __restrict__ w1t, float* __restrict__ w3t) {
    int i = blockIdx.x * 256 + threadIdx.x;
    if (i < 16384) {
        int oc = i >> 8, ic = i & 255;
        w1t[ic * 64 + oc] = w1[i];
    } else {
        int j = i - 16384;
        int oc = j >> 6, ic = j & 63;
        w3t[ic * 256 + oc] = w3[j];
    }
}

// ---- K1: conv1x1 256->64 + stats -------------------------------------------
// 16-pix tiles (grid 1568), 128 threads, K chunked x64. LDS 20KB -> many
// resident blocks per CU; inter-block overlap hides staging latency.
__global__ __launch_bounds__(128, 4) void k_conv1(const float* __restrict__ x,
        const float* __restrict__ w1t, float* __restrict__ y1, float* __restrict__ st) {
    __shared__ float xs[64][16];    // 4KB
    __shared__ float ws[64][64];    // 16KB
    int t = threadIdx.x, pb = blockIdx.x;
    int b = pb / 196, hw0 = (pb % 196) * 16;
    int tx = t & 7, ty = t >> 3;    // pix pair (8x2=16) / oc quad (16x4=64)
    float a0[4], a1[4];
    #pragma unroll
    for (int j = 0; j < 4; j++) { a0[j] = 0.f; a1[j] = 0.f; }
    #pragma unroll 1
    for (int cc = 0; cc < 4; cc++) {
        #pragma unroll
        for (int i = 0; i < 8; i++) {
            int e = i * 128 + t, c = e >> 4, p = e & 15;
            xs[c][p] = x[((b * 256) + cc * 64 + c) * HW + hw0 + p];
        }
        #pragma unroll
        for (int i = 0; i < 8; i++) {
            int e = i * 128 + t, ic = e >> 4, q = e & 15;
            *(float4*)&ws[ic][q * 4] = *(const float4*)&w1t[(cc * 64 + ic) * 64 + q * 4];
        }
        __syncthreads();
        #pragma unroll 8
        for (int c = 0; c < 64; c++) {
            float2 xv = *(const float2*)&xs[c][tx * 2];
            float4 wv = *(const float4*)&ws[c][ty * 4];
            float wa[4] = {wv.x, wv.y, wv.z, wv.w};
            #pragma unroll
            for (int j = 0; j < 4; j++) {
                a0[j] = fmaf(wa[j], xv.x, a0[j]);
                a1[j] = fmaf(wa[j], xv.y, a1[j]);
            }
        }
        __syncthreads();
    }
    #pragma unroll
    for (int j = 0; j < 4; j++) {
        int oc = ty * 4 + j;
        float2 o = make_float2(a0[j], a1[j]);
        *(float2*)&y1[((b * 64) + oc) * HW + hw0 + tx * 2] = o;
        float s = o.x + o.y;
        float q = o.x * o.x + o.y * o.y;
        #pragma unroll
        for (int off = 1; off <= 4; off <<= 1) {   // reduce over 8 tx lanes
            s += __shfl_xor(s, off, 64);
            q += __shfl_xor(q, off, 64);
        }
        if (tx == 0) {
            atomicAdd(&st[ACC1 + oc], s);
            atomicAdd(&st[ACC1 + 64 + oc], q);
        }
    }
}

// ---- finalize BN stats -> per-channel affine (a,b) -------------------------
__global__ void k_fin(const float* __restrict__ acc, float* __restrict__ fin,
                      const float* __restrict__ gamma, const float* __restrict__ beta, int C) {
    int c = threadIdx.x;
    if (c < C) {
        float mean = acc[c] * (1.0f / (float)NPIX);
        float var  = acc[C + c] * (1.0f / (float)NPIX) - mean * mean;
        float rstd = rsqrtf(var + 1e-5f);
        float a = gamma[c] * rstd;
        fin[c] = a;
        fin[C + c] = beta[c] - mean * a;
    }
}

// ---- K3: apply BN1+ReLU in-place, conv 64->16 + stats ----------------------
// 16-pix tiles, grid 1568, 128 threads. wsh padded to 68 cols (bank fix).
__global__ __launch_bounds__(128, 4) void k_bn1_convr(float* __restrict__ y1,
        const float* __restrict__ wr, float* __restrict__ tr, float* __restrict__ st) {
    __shared__ float ys[64][16];    // 4KB, BN1+ReLU applied
    __shared__ float wsh[16][68];   // [oc][ic] padded
    int t = threadIdx.x, pb = blockIdx.x;
    int b = pb / 196, hw0 = (pb % 196) * 16;
    int tx = t & 7, ty = t >> 3;    // pix pair / oc (16)
    #pragma unroll
    for (int i = 0; i < 8; i++) {
        int e = i * 128 + t, c = e >> 4, p = e & 15;
        int gi = ((b * 64) + c) * HW + hw0 + p;
        float v = y1[gi];
        v = fmaxf(st[FIN1 + c] * v + st[FIN1 + 64 + c], 0.f);
        ys[c][p] = v;
        y1[gi] = v;                 // y1 becomes y1r
    }
    #pragma unroll
    for (int i = 0; i < 8; i++) {
        int e = i * 128 + t;
        wsh[e >> 6][e & 63] = wr[e];
    }
    __syncthreads();
    float a0 = 0.f, a1 = 0.f;
    #pragma unroll 8
    for (int c = 0; c < 64; c++) {
        float2 yv = *(const float2*)&ys[c][tx * 2];
        float wv = wsh[ty][c];
        a0 = fmaf(wv, yv.x, a0);
        a1 = fmaf(wv, yv.y, a1);
    }
    *(float2*)&tr[((b * 16) + ty) * HW + hw0 + tx * 2] = make_float2(a0, a1);
    float s = a0 + a1;
    float q = a0 * a0 + a1 * a1;
    #pragma unroll
    for (int off = 1; off <= 4; off <<= 1) {
        s += __shfl_xor(s, off, 64);
        q += __shfl_xor(q, off, 64);
    }
    if (tx == 0) {
        atomicAdd(&st[ACCR + ty], s);
        atomicAdd(&st[ACCR + 16 + ty], q);
    }
}

// ---- K6: fused BNr+ReLU -> span conv (kernels in regs) -> involution + stats
// 4-channel split: grid 1792, LDS ~29KB -> ~5 blocks/CU.
__global__ __launch_bounds__(256) void k_invol(const float* __restrict__ y1r,
        const float* __restrict__ tr, const float* __restrict__ wsp,
        float* __restrict__ out2, float* __restrict__ st) {
    __shared__ float ts[16][256];      // BNr+ReLU'd tr tile (224 used)
    __shared__ float sw[49][16];       // span weights for this group
    __shared__ float ps[4][10][64];    // y1r halo tile (4 channels)
    __shared__ float red[4][8];
    int t = threadIdx.x, bidx = blockIdx.x;     // (((b*4+g)*14 + ht)*4 + h)
    int h = bidx & 3, r2 = bidx >> 2;
    int ht = r2 % 14;
    int bg = r2 / 14;
    int g = bg & 3, b = bg >> 2;
    int h0 = ht * 4;
    int c0 = h * 4;                    // channel offset within group
    // stage ts (BNr+ReLU applied) — all 16 channels (needed for kernel gen)
    #pragma unroll
    for (int i = 0; i < 16; i++) {
        int e = i * 256 + t, c = e >> 8, p = e & 255;
        if (p < 224) {
            float v = tr[((b * 16) + c) * HW + h0 * 56 + p];
            ts[c][p] = fmaxf(st[FINR + c] * v + st[FINR + 16 + c], 0.f);
        }
    }
    // stage span weights (group g): contiguous 784 floats
    for (int e = t; e < 784; e += 256) sw[e >> 4][e & 15] = wsp[g * 784 + e];
    // stage y1r halo for this block's 4 channels
    #pragma unroll
    for (int i = 0; i < 10; i++) {
        int e = i * 256 + t;
        int c = e / 640, rem = e - c * 640;
        int r = rem >> 6, wc = rem & 63;
        int gh = h0 + r - 3, gw = wc - 3;
        float v = 0.f;
        if (gh >= 0 && gh < 56 && gw >= 0 && gw < 56)
            v = y1r[((b * 64) + g * 16 + c0 + c) * HW + gh * 56 + gw];
        ps[c][r][wc] = v;
    }
    __syncthreads();
    float accv[4];
    #pragma unroll
    for (int c = 0; c < 4; c++) accv[c] = 0.f;
    bool active = t < 224;
    if (active) {
        int lh = t / 56, lw = t % 56;
        // per-pixel kernel generation into registers (uses all 16 channels)
        float tsr[16];
        #pragma unroll
        for (int c = 0; c < 16; c++) tsr[c] = ts[c][t];
        float kr[49];
        #pragma unroll
        for (int k = 0; k < 49; k++) {
            const float4* swr = (const float4*)&sw[k][0];
            float4 u0 = swr[0], u1 = swr[1], u2 = swr[2], u3 = swr[3];
            float v = u0.x * tsr[0];
            v = fmaf(u0.y, tsr[1], v);  v = fmaf(u0.z, tsr[2], v);  v = fmaf(u0.w, tsr[3], v);
            v = fmaf(u1.x, tsr[4], v);  v = fmaf(u1.y, tsr[5], v);  v = fmaf(u1.z, tsr[6], v);
            v = fmaf(u1.w, tsr[7], v);  v = fmaf(u2.x, tsr[8], v);  v = fmaf(u2.y, tsr[9], v);
            v = fmaf(u2.z, tsr[10], v); v = fmaf(u2.w, tsr[11], v); v = fmaf(u3.x, tsr[12], v);
            v = fmaf(u3.y, tsr[13], v); v = fmaf(u3.z, tsr[14], v); v = fmaf(u3.w, tsr[15], v);
            kr[k] = v;
        }
        // involution MAC over this block's 4 channels
        #pragma unroll
        for (int k = 0; k < 49; k++) {
            int ki = k / 7, kj = k % 7;
            float kv = kr[k];
            #pragma unroll
            for (int c = 0; c < 4; c++)
                accv[c] = fmaf(kv, ps[c][lh + ki][lw + kj], accv[c]);
        }
        int hw = h0 * 56 + t;
        #pragma unroll
        for (int c = 0; c < 4; c++)
            out2[((b * 64) + g * 16 + c0 + c) * HW + hw] = accv[c];
    }
    int wave = t >> 6, lane = t & 63;
    #pragma unroll
    for (int c = 0; c < 4; c++) {
        float v = active ? accv[c] : 0.f;
        float s  = wave_sum(v);
        float s2 = wave_sum(v * v);
        if (lane == 0) { red[wave][c] = s; red[wave][4 + c] = s2; }
    }
    __syncthreads();
    if (t < 8) {
        float s = red[0][t] + red[1][t] + red[2][t] + red[3][t];
        int c = t & 3, isq = t >> 2;
        atomicAdd(&st[ACC2 + isq * 64 + g * 16 + c0 + c], s);
    }
}

// ---- K7: apply BN2+ReLU, conv 64->256 + stats ------------------------------
// 16-pix tiles x 4 oc-splits: grid 6272, 128 threads, single stage (K=64),
// barrier-free compute loop. BN2+ReLU applied during staging.
__global__ __launch_bounds__(128, 4) void k_bn2_conv3(const float* __restrict__ out2,
        const float* __restrict__ w3t, float* __restrict__ y3, float* __restrict__ st) {
    __shared__ float xs[64][16];    // 4KB, BN2+ReLU applied
    __shared__ float ws[64][64];    // 16KB, [ic][oc-chunk]
    int t = threadIdx.x, blk = blockIdx.x;
    int os = blk & 3, pb = blk >> 2;
    int b = pb / 196, hw0 = (pb % 196) * 16;
    int tx = t & 7, ty = t >> 3;    // pix pair / oc quad
    #pragma unroll
    for (int i = 0; i < 8; i++) {
        int e = i * 128 + t, c = e >> 4, p = e & 15;
        float v = out2[((b * 64) + c) * HW + hw0 + p];
        xs[c][p] = fmaxf(st[FIN2 + c] * v + st[FIN2 + 64 + c], 0.f);
    }
    #pragma unroll
    for (int i = 0; i < 8; i++) {
        int e = i * 128 + t, ic = e >> 4, q = e & 15;
        *(float4*)&ws[ic][q * 4] = *(const float4*)&w3t[ic * 256 + os * 64 + q * 4];
    }
    __syncthreads();
    float a0[4], a1[4];
    #pragma unroll
    for (int j = 0; j < 4; j++) { a0[j] = 0.f; a1[j] = 0.f; }
    #pragma unroll 8
    for (int c = 0; c < 64; c++) {
        float2 xv = *(const float2*)&xs[c][tx * 2];
        float4 wv = *(const float4*)&ws[c][ty * 4];
        float wa[4] = {wv.x, wv.y, wv.z, wv.w};
        #pragma unroll
        for (int j = 0; j < 4; j++) {
            a0[j] = fmaf(wa[j], xv.x, a0[j]);
            a1[j] = fmaf(wa[j], xv.y, a1[j]);
        }
    }
    #pragma unroll
    for (int j = 0; j < 4; j++) {
        int oc = os * 64 + ty * 4 + j;
        float2 o = make_float2(a0[j], a1[j]);
        *(float2*)&y3[((b * 256) + oc) * HW + hw0 + tx * 2] = o;
        float s = o.x + o.y;
        float q = o.x * o.x + o.y * o.y;
        #pragma unroll
        for (int off = 1; off <= 4; off <<= 1) {
            s += __shfl_xor(s, off, 64);
            q += __shfl_xor(q, off, 64);
        }
        if (tx == 0) {
            atomicAdd(&st[ACC3 + oc], s);
            atomicAdd(&st[ACC3 + 256 + oc], q);
        }
    }
}

// ---- K9: BN3 + residual + ReLU (float4) ------------------------------------
__global__ __launch_bounds__(256) void k_final(const float* __restrict__ y3,
        const float* __restrict__ x, float* __restrict__ out, const float* __restrict__ st) {
    int idx = blockIdx.x * 256 + threadIdx.x;   // float4 index
    if (idx < 1605632) {
        int c = (idx / 784) & 255;
        float a = st[FIN3 + c], bb = st[FIN3 + 256 + c];
        float4 v  = ((const float4*)y3)[idx];
        float4 xv = ((const float4*)x)[idx];
        float4 o;
        o.x = fmaxf(a * v.x + bb + xv.x, 0.f);
        o.y = fmaxf(a * v.y + bb + xv.y, 0.f);
        o.z = fmaxf(a * v.z + bb + xv.z, 0.f);
        o.w = fmaxf(a * v.w + bb + xv.w, 0.f);
        ((float4*)out)[idx] = o;
    }
}

extern "C" void kernel_launch(void* const* d_in, const int* in_sizes, int n_in,
                              void* d_out, int out_size, void* d_ws, size_t ws_size,
                              hipStream_t stream) {
    const float* x   = (const float*)d_in[0];
    const float* w1  = (const float*)d_in[1];
    const float* g1  = (const float*)d_in[2];
    const float* b1  = (const float*)d_in[3];
    const float* wr  = (const float*)d_in[4];
    const float* gr  = (const float*)d_in[5];
    const float* br  = (const float*)d_in[6];
    const float* wsp = (const float*)d_in[7];
    const float* g2  = (const float*)d_in[8];
    const float* b2  = (const float*)d_in[9];
    const float* w3  = (const float*)d_in[10];
    const float* g3  = (const float*)d_in[11];
    const float* b3  = (const float*)d_in[12];
    float* out = (float*)d_out;
    float* w   = (float*)d_ws;
    float* y1   = w + OFF_Y1;
    float* tr   = w + OFF_TR;
    float* w1t  = w + OFF_WT;
    float* w3t  = w + OFF_WT + 16384;
    float* out2 = w + OFF_OUT2;
    float* y3   = w + OFF_Y3;
    float* st   = w + OFF_ST;

    hipMemsetAsync(st, 0, 2048 * sizeof(float), stream);
    k_wt<<<128, 256, 0, stream>>>(w1, w3, w1t, w3t);
    k_conv1<<<1568, 128, 0, stream>>>(x, w1t, y1, st);
    k_fin<<<1, 64, 0, stream>>>(st + ACC1, st + FIN1, g1, b1, 64);
    k_bn1_convr<<<1568, 128, 0, stream>>>(y1, wr, tr, st);
    k_fin<<<1, 64, 0, stream>>>(st + ACCR, st + FINR, gr, br, 16);
    k_invol<<<1792, 256, 0, stream>>>(y1, tr, wsp, out2, st);
    k_fin<<<1, 64, 0, stream>>>(st + ACC2, st + FIN2, g2, b2, 64);
    k_bn2_conv3<<<6272, 128, 0, stream>>>(out2, w3t, y3, st);
    k_fin<<<1, 256, 0, stream>>>(st + ACC3, st + FIN3, g3, b3, 256);
    k_final<<<6272, 256, 0, stream>>>(y3, x, out, st);
}

// Round 10
// 275.086 us; speedup vs baseline: 1.9043x; 1.9043x over previous
//
#include <hip/hip_runtime.h>

#define HW 3136          // 56*56
#define NPIX 25088       // 8*3136
#define NBLK 392         // NPIX/64

// workspace float offsets
#define OFF_Y1   0u
#define OFF_TR   1605632u
#define OFF_WT   2007040u      // w1t (16384) + w3t (16384)
#define OFF_OUT2 6924288u
#define OFF_Y3   8529920u
#define OFF_ST   14952448u
// stats sub-offsets (floats, relative to st base). acc: [C]=sum, [C..2C)=sumsq
#define ACC1 0
#define ACCR 128
#define ACC2 160
#define ACC3 288
#define FIN1 800
#define FINR 928
#define FIN2 960
#define FIN3 1088

__device__ __forceinline__ float wave_sum(float v) {
    #pragma unroll
    for (int off = 32; off > 0; off >>= 1) v += __shfl_xor(v, off, 64);
    return v;
}

// async global->LDS, 16B per lane; dst is wave-uniform base, HW adds lane*16.
__device__ __forceinline__ void gl_lds16(const float* g, float* l) {
    __builtin_amdgcn_global_load_lds(
        (const __attribute__((address_space(1))) unsigned int*)g,
        (__attribute__((address_space(3))) unsigned int*)l, 16, 0, 0);
}

// ---- K0: transpose weights w1[64][256]->w1t[256][64], w3[256][64]->w3t[64][256]
__global__ __launch_bounds__(256) void k_wt(const float* __restrict__ w1,
        const float* __restrict__ w3, float* __restrict__ w1t, float* __restrict__ w3t) {
    int i = blockIdx.x * 256 + threadIdx.x;
    if (i < 16384) {
        int oc = i >> 8, ic = i & 255;
        w1t[ic * 64 + oc] = w1[i];
    } else {
        int j = i - 16384;
        int oc = j >> 6, ic = j & 63;
        w3t[ic * 256 + oc] = w3[j];
    }
}

// ---- K1: conv1x1 256->64 + stats -------------------------------------------
// 64-pix tile, 256 threads, 4x4 thread tile (R5 base) + LDS double-buffer via
// global_load_lds: chunk cc+1 issued before compute of cc, drained at barrier.
__global__ __launch_bounds__(256) void k_conv1(const float* __restrict__ x,
        const float* __restrict__ w1t, float* __restrict__ y1, float* __restrict__ st) {
    __shared__ float xs[2][64][64];   // 32KB
    __shared__ float ws[2][64][64];   // 32KB
    int t = threadIdx.x, pb = blockIdx.x;
    int b = pb / 49, hw0 = (pb % 49) * 64;
    int tx = t & 15, ty = t >> 4;
    int wv = t >> 6, ln = t & 63;

    // stage chunk cc into buffer buf: 16 x 1KB segments (4 per wave)
    #define STAGE(cc, buf)                                                        \
        _Pragma("unroll")                                                         \
        for (int i = 0; i < 4; i++) {                                             \
            int s = i * 4 + wv;                                                   \
            const float* gx = x + (size_t)((b * 256) + (cc) * 64 + s * 4 + (ln >> 4)) * HW \
                              + hw0 + (ln & 15) * 4;                              \
            gl_lds16(gx, &xs[buf][s * 4][0]);                                     \
            const float* gw = w1t + ((cc) * 64 + s * 4) * 64 + ln * 4;            \
            gl_lds16(gw, &ws[buf][s * 4][0]);                                     \
        }

    STAGE(0, 0);
    __syncthreads();                  // drains vmcnt(0)
    float acc[4][4];
    #pragma unroll
    for (int i = 0; i < 4; i++)
        #pragma unroll
        for (int j = 0; j < 4; j++) acc[i][j] = 0.f;
    #pragma unroll 1
    for (int cc = 0; cc < 4; cc++) {
        int cur = cc & 1;
        if (cc < 3) STAGE(cc + 1, cur ^ 1);   // async prefetch, no wait
        #pragma unroll 8
        for (int c = 0; c < 64; c++) {
            float4 xv = *(const float4*)&xs[cur][c][tx * 4];
            float4 wv4 = *(const float4*)&ws[cur][c][ty * 4];
            float xa[4] = {xv.x, xv.y, xv.z, xv.w};
            float wa[4] = {wv4.x, wv4.y, wv4.z, wv4.w};
            #pragma unroll
            for (int i = 0; i < 4; i++)
                #pragma unroll
                for (int j = 0; j < 4; j++) acc[i][j] = fmaf(wa[i], xa[j], acc[i][j]);
        }
        __syncthreads();              // drains prefetch + protects LDS reuse
    }
    #undef STAGE
    #pragma unroll
    for (int i = 0; i < 4; i++) {
        int oc = ty * 4 + i;
        float4 o = make_float4(acc[i][0], acc[i][1], acc[i][2], acc[i][3]);
        *(float4*)&y1[((b * 64) + oc) * HW + hw0 + tx * 4] = o;
        float s = o.x + o.y + o.z + o.w;
        float q = o.x * o.x + o.y * o.y + o.z * o.z + o.w * o.w;
        #pragma unroll
        for (int off = 1; off <= 8; off <<= 1) {
            s += __shfl_xor(s, off, 64);
            q += __shfl_xor(q, off, 64);
        }
        if (tx == 0) {
            atomicAdd(&st[ACC1 + oc], s);
            atomicAdd(&st[ACC1 + 64 + oc], q);
        }
    }
}

// ---- finalize BN stats -> per-channel affine (a,b) -------------------------
__global__ void k_fin(const float* __restrict__ acc, float* __restrict__ fin,
                      const float* __restrict__ gamma, const float* __restrict__ beta, int C) {
    int c = threadIdx.x;
    if (c < C) {
        float mean = acc[c] * (1.0f / (float)NPIX);
        float var  = acc[C + c] * (1.0f / (float)NPIX) - mean * mean;
        float rstd = rsqrtf(var + 1e-5f);
        float a = gamma[c] * rstd;
        fin[c] = a;
        fin[C + c] = beta[c] - mean * a;
    }
}

// ---- K3: conv 64->16 + stats (BN1+ReLU applied on load; y1 stays raw) ------
__global__ __launch_bounds__(256, 4) void k_bn1_convr(const float* __restrict__ y1,
        const float* __restrict__ wr, float* __restrict__ tr, float* __restrict__ st) {
    __shared__ float ys[64][64];    // [ic][pix], BN1+ReLU applied
    __shared__ float wsh[16][64];   // [oc][ic]
    int t = threadIdx.x, pb = blockIdx.x;
    int b = pb / 49, hw0 = (pb % 49) * 64;
    int tx = t & 15, ty = t >> 4;   // pix group (4 pix) / oc (one of 16)
    #pragma unroll
    for (int i = 0; i < 16; i++) {
        int e = i * 256 + t, c = e >> 6, p = e & 63;
        float v = y1[((b * 64) + c) * HW + hw0 + p];
        ys[c][p] = fmaxf(st[FIN1 + c] * v + st[FIN1 + 64 + c], 0.f);
    }
    #pragma unroll
    for (int i = 0; i < 4; i++) {
        int e = i * 256 + t;
        wsh[e >> 6][e & 63] = wr[e];
    }
    __syncthreads();
    float a0 = 0.f, a1 = 0.f, a2 = 0.f, a3 = 0.f;
    #pragma unroll 8
    for (int c = 0; c < 64; c++) {
        float4 yv = *(const float4*)&ys[c][tx * 4];
        float wv = wsh[ty][c];
        a0 = fmaf(wv, yv.x, a0); a1 = fmaf(wv, yv.y, a1);
        a2 = fmaf(wv, yv.z, a2); a3 = fmaf(wv, yv.w, a3);
    }
    *(float4*)&tr[((b * 16) + ty) * HW + hw0 + tx * 4] = make_float4(a0, a1, a2, a3);
    float s = a0 + a1 + a2 + a3;
    float q = a0 * a0 + a1 * a1 + a2 * a2 + a3 * a3;
    #pragma unroll
    for (int off = 1; off <= 8; off <<= 1) {
        s += __shfl_xor(s, off, 64);
        q += __shfl_xor(q, off, 64);
    }
    if (tx == 0) {
        atomicAdd(&st[ACCR + ty], s);
        atomicAdd(&st[ACCR + 16 + ty], q);
    }
}

// ---- K6: fused BNr+ReLU -> span conv (kernels in regs) -> involution + stats
// 8-channel split (grid 896). y1 is RAW: BN1+ReLU applied when staging ps.
__global__ __launch_bounds__(256) void k_invol(const float* __restrict__ y1,
        const float* __restrict__ tr, const float* __restrict__ wsp,
        float* __restrict__ out2, float* __restrict__ st) {
    __shared__ float ts[16][256];      // BNr+ReLU'd tr tile (224 used)
    __shared__ float sw[49][16];       // span weights for this group
    __shared__ float ps[8][10][64];    // y1r halo tile (8 channels)
    __shared__ float red[4][16];
    int t = threadIdx.x, bidx = blockIdx.x;     // (((b*4+g)*14 + ht)*2 + h)
    int h = bidx & 1, r2 = bidx >> 1;
    int ht = r2 % 14;
    int bg = r2 / 14;
    int g = bg & 3, b = bg >> 2;
    int h0 = ht * 4;
    int c0 = h * 8;                    // channel offset within group
    // stage ts (BNr+ReLU applied)
    #pragma unroll
    for (int i = 0; i < 16; i++) {
        int e = i * 256 + t, c = e >> 8, p = e & 255;
        if (p < 224) {
            float v = tr[((b * 16) + c) * HW + h0 * 56 + p];
            ts[c][p] = fmaxf(st[FINR + c] * v + st[FINR + 16 + c], 0.f);
        }
    }
    // stage span weights (group g): contiguous 784 floats
    for (int e = t; e < 784; e += 256) sw[e >> 4][e & 15] = wsp[g * 784 + e];
    // stage y1 halo (BN1+ReLU applied) for this block's 8 channels
    for (int i = 0; i < 20; i++) {
        int e = i * 256 + t;
        int c = e / 640, rem = e - c * 640;
        int r = rem >> 6, wc = rem & 63;
        int gh = h0 + r - 3, gw = wc - 3;
        float v = 0.f;
        if (gh >= 0 && gh < 56 && gw >= 0 && gw < 56) {
            int ch = g * 16 + c0 + c;
            float raw = y1[((b * 64) + ch) * HW + gh * 56 + gw];
            v = fmaxf(st[FIN1 + ch] * raw + st[FIN1 + 64 + ch], 0.f);
        }
        ps[c][r][wc] = v;
    }
    __syncthreads();
    float accv[8];
    #pragma unroll
    for (int c = 0; c < 8; c++) accv[c] = 0.f;
    bool active = t < 224;
    if (active) {
        int lh = t / 56, lw = t % 56;
        // per-pixel kernel generation into registers (uses all 16 channels)
        float tsr[16];
        #pragma unroll
        for (int c = 0; c < 16; c++) tsr[c] = ts[c][t];
        float kr[49];
        #pragma unroll
        for (int k = 0; k < 49; k++) {
            const float4* swr = (const float4*)&sw[k][0];
            float4 u0 = swr[0], u1 = swr[1], u2 = swr[2], u3 = swr[3];
            float v = u0.x * tsr[0];
            v = fmaf(u0.y, tsr[1], v);  v = fmaf(u0.z, tsr[2], v);  v = fmaf(u0.w, tsr[3], v);
            v = fmaf(u1.x, tsr[4], v);  v = fmaf(u1.y, tsr[5], v);  v = fmaf(u1.z, tsr[6], v);
            v = fmaf(u1.w, tsr[7], v);  v = fmaf(u2.x, tsr[8], v);  v = fmaf(u2.y, tsr[9], v);
            v = fmaf(u2.z, tsr[10], v); v = fmaf(u2.w, tsr[11], v); v = fmaf(u3.x, tsr[12], v);
            v = fmaf(u3.y, tsr[13], v); v = fmaf(u3.z, tsr[14], v); v = fmaf(u3.w, tsr[15], v);
            kr[k] = v;
        }
        // involution MAC over this block's 8 channels
        #pragma unroll
        for (int k = 0; k < 49; k++) {
            int ki = k / 7, kj = k % 7;
            float kv = kr[k];
            #pragma unroll
            for (int c = 0; c < 8; c++)
                accv[c] = fmaf(kv, ps[c][lh + ki][lw + kj], accv[c]);
        }
        int hw = h0 * 56 + t;
        #pragma unroll
        for (int c = 0; c < 8; c++)
            out2[((b * 64) + g * 16 + c0 + c) * HW + hw] = accv[c];
    }
    int wave = t >> 6, lane = t & 63;
    #pragma unroll
    for (int c = 0; c < 8; c++) {
        float v = active ? accv[c] : 0.f;
        float s  = wave_sum(v);
        float s2 = wave_sum(v * v);
        if (lane == 0) { red[wave][c] = s; red[wave][8 + c] = s2; }
    }
    __syncthreads();
    if (t < 16) {
        float s = red[0][t] + red[1][t] + red[2][t] + red[3][t];
        int c = t & 7, isq = t >> 3;
        atomicAdd(&st[ACC2 + isq * 64 + g * 16 + c0 + c], s);
    }
}

// ---- K7: apply BN2+ReLU, conv 64->256 + stats ------------------------------
// occ chunk on grid (blockIdx & 3): one staging + barrier-free 64-iter loop.
__global__ __launch_bounds__(256, 4) void k_bn2_conv3(const float* __restrict__ out2,
        const float* __restrict__ w3t, float* __restrict__ y3, float* __restrict__ st) {
    __shared__ float os[64][64];    // [ic][pix], BN2+ReLU applied
    __shared__ float wst[64][64];   // [ic][oc-chunk]
    int t = threadIdx.x, blk = blockIdx.x;
    int occ = blk & 3, pb = blk >> 2;
    int b = pb / 49, hw0 = (pb % 49) * 64;
    int tx = t & 15, ty = t >> 4;
    #pragma unroll
    for (int i = 0; i < 16; i++) {
        int e = i * 256 + t, c = e >> 6, p = e & 63;
        float v = out2[((b * 64) + c) * HW + hw0 + p];
        os[c][p] = fmaxf(st[FIN2 + c] * v + st[FIN2 + 64 + c], 0.f);
        wst[c][p] = w3t[c * 256 + occ * 64 + p];
    }
    __syncthreads();
    float acc[4][4];
    #pragma unroll
    for (int i = 0; i < 4; i++)
        #pragma unroll
        for (int j = 0; j < 4; j++) acc[i][j] = 0.f;
    #pragma unroll 8
    for (int c = 0; c < 64; c++) {
        float4 xv = *(const float4*)&os[c][tx * 4];
        float4 wv = *(const float4*)&wst[c][ty * 4];
        float xa[4] = {xv.x, xv.y, xv.z, xv.w};
        float wa[4] = {wv.x, wv.y, wv.z, wv.w};
        #pragma unroll
        for (int i = 0; i < 4; i++)
            #pragma unroll
            for (int j = 0; j < 4; j++) acc[i][j] = fmaf(wa[i], xa[j], acc[i][j]);
    }
    #pragma unroll
    for (int i = 0; i < 4; i++) {
        int oc = occ * 64 + ty * 4 + i;
        float4 o = make_float4(acc[i][0], acc[i][1], acc[i][2], acc[i][3]);
        *(float4*)&y3[((b * 256) + oc) * HW + hw0 + tx * 4] = o;
        float s = o.x + o.y + o.z + o.w;
        float q = o.x * o.x + o.y * o.y + o.z * o.z + o.w * o.w;
        #pragma unroll
        for (int off = 1; off <= 8; off <<= 1) {
            s += __shfl_xor(s, off, 64);
            q += __shfl_xor(q, off, 64);
        }
        if (tx == 0) {
            atomicAdd(&st[ACC3 + oc], s);
            atomicAdd(&st[ACC3 + 256 + oc], q);
        }
    }
}

// ---- K9: BN3 + residual + ReLU (float4) ------------------------------------
__global__ __launch_bounds__(256) void k_final(const float* __restrict__ y3,
        const float* __restrict__ x, float* __restrict__ out, const float* __restrict__ st) {
    int idx = blockIdx.x * 256 + threadIdx.x;   // float4 index
    if (idx < 1605632) {
        int c = (idx / 784) & 255;
        float a = st[FIN3 + c], bb = st[FIN3 + 256 + c];
        float4 v  = ((const float4*)y3)[idx];
        float4 xv = ((const float4*)x)[idx];
        float4 o;
        o.x = fmaxf(a * v.x + bb + xv.x, 0.f);
        o.y = fmaxf(a * v.y + bb + xv.y, 0.f);
        o.z = fmaxf(a * v.z + bb + xv.z, 0.f);
        o.w = fmaxf(a * v.w + bb + xv.w, 0.f);
        ((float4*)out)[idx] = o;
    }
}

extern "C" void kernel_launch(void* const* d_in, const int* in_sizes, int n_in,
                              void* d_out, int out_size, void* d_ws, size_t ws_size,
                              hipStream_t stream) {
    const float* x   = (const float*)d_in[0];
    const float* w1  = (const float*)d_in[1];
    const float* g1  = (const float*)d_in[2];
    const float* b1  = (const float*)d_in[3];
    const float* wr  = (const float*)d_in[4];
    const float* gr  = (const float*)d_in[5];
    const float* br  = (const float*)d_in[6];
    const float* wsp = (const float*)d_in[7];
    const float* g2  = (const float*)d_in[8];
    const float* b2  = (const float*)d_in[9];
    const float* w3  = (const float*)d_in[10];
    const float* g3  = (const float*)d_in[11];
    const float* b3  = (const float*)d_in[12];
    float* out = (float*)d_out;
    float* w   = (float*)d_ws;
    float* y1   = w + OFF_Y1;
    float* tr   = w + OFF_TR;
    float* w1t  = w + OFF_WT;
    float* w3t  = w + OFF_WT + 16384;
    float* out2 = w + OFF_OUT2;
    float* y3   = w + OFF_Y3;
    float* st   = w + OFF_ST;

    hipMemsetAsync(st, 0, 2048 * sizeof(float), stream);
    k_wt<<<128, 256, 0, stream>>>(w1, w3, w1t, w3t);
    k_conv1<<<NBLK, 256, 0, stream>>>(x, w1t, y1, st);
    k_fin<<<1, 64, 0, stream>>>(st + ACC1, st + FIN1, g1, b1, 64);
    k_bn1_convr<<<NBLK, 256, 0, stream>>>(y1, wr, tr, st);
    k_fin<<<1, 64, 0, stream>>>(st + ACCR, st + FINR, gr, br, 16);
    k_invol<<<896, 256, 0, stream>>>(y1, tr, wsp, out2, st);
    k_fin<<<1, 64, 0, stream>>>(st + ACC2, st + FIN2, g2, b2, 64);
    k_bn2_conv3<<<NBLK * 4, 256, 0, stream>>>(out2, w3t, y3, st);
    k_fin<<<1, 256, 0, stream>>>(st + ACC3, st + FIN3, g3, b3, 256);
    k_final<<<6272, 256, 0, stream>>>(y3, x, out, st);
}

// Round 11
// 274.530 us; speedup vs baseline: 1.9081x; 1.0020x over previous
//
#include <hip/hip_runtime.h>

#define HW 3136          // 56*56
#define NPIX 25088       // 8*3136
#define NBLK 392

typedef float f32x4 __attribute__((ext_vector_type(4)));
typedef short short8 __attribute__((ext_vector_type(8)));

// workspace float offsets
#define OFF_Y1    0u
#define OFF_TR    1605632u
#define OFF_W1BF  2007040u
#define OFF_W3BF  2015232u
#define OFF_XT    2023424u      // 25088x256 bf16 (pre-swizzled per 64-pix tile)
#define OFF_OUT2T 5234688u     // 25088x64 bf16 (linear)
#define OFF_Y3    6037504u
#define OFF_ST    12460032u
// stats sub-offsets
#define ACC1 0
#define ACCR 128
#define ACC2 160
#define ACC3 288
#define FIN1 800
#define FINR 928
#define FIN2 960
#define FIN3 1088

__device__ __forceinline__ float wave_sum(float v) {
    #pragma unroll
    for (int off = 32; off > 0; off >>= 1) v += __shfl_xor(v, off, 64);
    return v;
}
__device__ __forceinline__ unsigned short f2bf(float f) {   // RNE
    unsigned u = __float_as_uint(f);
    u += 0x7FFFu + ((u >> 16) & 1u);
    return (unsigned short)(u >> 16);
}
__device__ __forceinline__ float bf2f(unsigned h) {
    return __uint_as_float(h << 16);
}
__device__ __forceinline__ void gl_lds16(const void* g, void* l) {
    __builtin_amdgcn_global_load_lds(
        (const __attribute__((address_space(1))) unsigned int*)g,
        (__attribute__((address_space(3))) unsigned int*)l, 16, 0, 0);
}

// ---- K0: convert weights to bf16 (layouts already [M][K]) ------------------
__global__ __launch_bounds__(256) void k_prep(const float* __restrict__ w1,
        const float* __restrict__ w3, unsigned short* __restrict__ w1bf,
        unsigned short* __restrict__ w3bf) {
    int i = blockIdx.x * 256 + threadIdx.x;
    if (i < 16384) w1bf[i] = f2bf(w1[i]);
    else w3bf[i - 16384] = f2bf(w3[i - 16384]);
}

// ---- K_tx: x[ic][pix] fp32 -> xt[pix][ic] bf16, pre-swizzled ---------------
__global__ __launch_bounds__(256) void k_tx(const float* __restrict__ x,
        unsigned short* __restrict__ xt) {
    __shared__ float lt[64][65];
    int t = threadIdx.x, bidx = blockIdx.x;
    int ict = bidx & 3, r = bidx >> 2;
    int pt = r % 49, b = r / 49;
    int pix0 = pt * 64, ic0 = ict * 64;
    #pragma unroll
    for (int i = 0; i < 16; i++) {
        int e = i * 256 + t, ic = e >> 6, p = e & 63;
        lt[ic][p] = x[(size_t)((b * 256) + ic0 + ic) * HW + pix0 + p];
    }
    __syncthreads();
    char* tb = (char*)xt + (size_t)(b * HW + pix0) * 512;
    #pragma unroll
    for (int i = 0; i < 2; i++) {
        int c = i * 256 + t;
        int p = c >> 3, q = c & 7;
        uint4 o;
        o.x = f2bf(lt[q * 8 + 0][p]) | ((unsigned)f2bf(lt[q * 8 + 1][p]) << 16);
        o.y = f2bf(lt[q * 8 + 2][p]) | ((unsigned)f2bf(lt[q * 8 + 3][p]) << 16);
        o.z = f2bf(lt[q * 8 + 4][p]) | ((unsigned)f2bf(lt[q * 8 + 5][p]) << 16);
        o.w = f2bf(lt[q * 8 + 6][p]) | ((unsigned)f2bf(lt[q * 8 + 7][p]) << 16);
        unsigned d = (unsigned)(p * 512 + (ic0 + q * 8) * 2) ^ (unsigned)((p & 7) << 4);
        *(uint4*)(tb + d) = o;
    }
}

// ---- K1: conv1x1 256->64 via MFMA 16x16x32 bf16 + stats --------------------
__global__ __launch_bounds__(256, 4) void k_conv1(const unsigned short* __restrict__ xt,
        const unsigned short* __restrict__ w1bf, float* __restrict__ y1,
        float* __restrict__ st) {
    __shared__ unsigned short xs[64 * 256];   // 32KB (swizzled image of xt tile)
    int t = threadIdx.x, pb = blockIdx.x;
    int b = pb / 49, hw0 = (pb % 49) * 64;
    int lane = t & 63, wv = t >> 6;
    int grp = lane >> 4, li = lane & 15;
    int oc0 = wv * 16;
    // A fragments (wave's 16-oc strip, all K) from global (L2-hot, 32KB total)
    short8 a[8];
    #pragma unroll
    for (int s = 0; s < 8; s++)
        a[s] = *(const short8*)(w1bf + (size_t)(oc0 + li) * 256 + s * 32 + grp * 8);
    // stage xt tile (contiguous 32KB) to LDS linearly
    const char* src = (const char*)xt + (size_t)(b * HW + hw0) * 512;
    char* dst = (char*)xs;
    #pragma unroll
    for (int i = 0; i < 8; i++)
        gl_lds16(src + wv * 8192 + i * 1024 + lane * 16, dst + wv * 8192 + i * 1024);
    __syncthreads();
    f32x4 acc[4];
    #pragma unroll
    for (int n = 0; n < 4; n++) acc[n] = (f32x4){0.f, 0.f, 0.f, 0.f};
    #pragma unroll
    for (int s = 0; s < 8; s++) {
        #pragma unroll
        for (int n = 0; n < 4; n++) {
            int row = n * 16 + li;
            unsigned o = (unsigned)(row * 512 + s * 64 + grp * 16) ^ (unsigned)((row & 7) << 4);
            short8 bf = *(const short8*)(dst + o);
            acc[n] = __builtin_amdgcn_mfma_f32_16x16x32_bf16(a[s], bf, acc[n], 0, 0, 0);
        }
    }
    // C layout: col=li, row(oc-local)=grp*4+r
    #pragma unroll
    for (int n = 0; n < 4; n++)
        #pragma unroll
        for (int r = 0; r < 4; r++)
            y1[(size_t)(b * 64 + oc0 + grp * 4 + r) * HW + hw0 + n * 16 + li] = acc[n][r];
    #pragma unroll
    for (int r = 0; r < 4; r++) {
        float s = acc[0][r] + acc[1][r] + acc[2][r] + acc[3][r];
        float q = acc[0][r] * acc[0][r] + acc[1][r] * acc[1][r]
                + acc[2][r] * acc[2][r] + acc[3][r] * acc[3][r];
        #pragma unroll
        for (int off = 1; off <= 8; off <<= 1) {
            s += __shfl_xor(s, off, 64);
            q += __shfl_xor(q, off, 64);
        }
        if (li == 0) {
            int oc = oc0 + grp * 4 + r;
            atomicAdd(&st[ACC1 + oc], s);
            atomicAdd(&st[ACC1 + 64 + oc], q);
        }
    }
}

// ---- finalize BN stats -> per-channel affine (a,b) -------------------------
__global__ void k_fin(const float* __restrict__ acc, float* __restrict__ fin,
                      const float* __restrict__ gamma, const float* __restrict__ beta, int C) {
    int c = threadIdx.x;
    if (c < C) {
        float mean = acc[c] * (1.0f / (float)NPIX);
        float var  = acc[C + c] * (1.0f / (float)NPIX) - mean * mean;
        float rstd = rsqrtf(var + 1e-5f);
        float a = gamma[c] * rstd;
        fin[c] = a;
        fin[C + c] = beta[c] - mean * a;
    }
}

// ---- K3: conv 64->16 + stats (BN1+ReLU applied on load; y1 stays raw) ------
__global__ __launch_bounds__(256, 4) void k_bn1_convr(const float* __restrict__ y1,
        const float* __restrict__ wr, float* __restrict__ tr, float* __restrict__ st) {
    __shared__ float ys[64][64];
    __shared__ float wsh[16][64];
    int t = threadIdx.x, pb = blockIdx.x;
    int b = pb / 49, hw0 = (pb % 49) * 64;
    int tx = t & 15, ty = t >> 4;
    #pragma unroll
    for (int i = 0; i < 16; i++) {
        int e = i * 256 + t, c = e >> 6, p = e & 63;
        float v = y1[((b * 64) + c) * HW + hw0 + p];
        ys[c][p] = fmaxf(st[FIN1 + c] * v + st[FIN1 + 64 + c], 0.f);
    }
    #pragma unroll
    for (int i = 0; i < 4; i++) {
        int e = i * 256 + t;
        wsh[e >> 6][e & 63] = wr[e];
    }
    __syncthreads();
    float a0 = 0.f, a1 = 0.f, a2 = 0.f, a3 = 0.f;
    #pragma unroll 8
    for (int c = 0; c < 64; c++) {
        float4 yv = *(const float4*)&ys[c][tx * 4];
        float wv = wsh[ty][c];
        a0 = fmaf(wv, yv.x, a0); a1 = fmaf(wv, yv.y, a1);
        a2 = fmaf(wv, yv.z, a2); a3 = fmaf(wv, yv.w, a3);
    }
    *(float4*)&tr[((b * 16) + ty) * HW + hw0 + tx * 4] = make_float4(a0, a1, a2, a3);
    float s = a0 + a1 + a2 + a3;
    float q = a0 * a0 + a1 * a1 + a2 * a2 + a3 * a3;
    #pragma unroll
    for (int off = 1; off <= 8; off <<= 1) {
        s += __shfl_xor(s, off, 64);
        q += __shfl_xor(q, off, 64);
    }
    if (tx == 0) {
        atomicAdd(&st[ACCR + ty], s);
        atomicAdd(&st[ACCR + 16 + ty], q);
    }
}

// ---- K6: fused BNr+ReLU -> span conv -> involution, out as bf16 transposed -
__global__ __launch_bounds__(256) void k_invol(const float* __restrict__ y1,
        const float* __restrict__ tr, const float* __restrict__ wsp,
        unsigned short* __restrict__ out2t, float* __restrict__ st) {
    __shared__ float ts[16][256];
    __shared__ float sw[49][16];
    __shared__ float ps[8][10][64];
    __shared__ float red[4][16];
    int t = threadIdx.x, bidx = blockIdx.x;
    int hh = bidx & 1, r2 = bidx >> 1;
    int ht = r2 % 14;
    int bg = r2 / 14;
    int g = bg & 3, b = bg >> 2;
    int h0 = ht * 4;
    int c0 = hh * 8;
    #pragma unroll
    for (int i = 0; i < 16; i++) {
        int e = i * 256 + t, c = e >> 8, p = e & 255;
        if (p < 224) {
            float v = tr[((b * 16) + c) * HW + h0 * 56 + p];
            ts[c][p] = fmaxf(st[FINR + c] * v + st[FINR + 16 + c], 0.f);
        }
    }
    for (int e = t; e < 784; e += 256) sw[e >> 4][e & 15] = wsp[g * 784 + e];
    for (int i = 0; i < 20; i++) {
        int e = i * 256 + t;
        int c = e / 640, rem = e - c * 640;
        int r = rem >> 6, wc = rem & 63;
        int gh = h0 + r - 3, gw = wc - 3;
        float v = 0.f;
        if (gh >= 0 && gh < 56 && gw >= 0 && gw < 56) {
            int ch = g * 16 + c0 + c;
            float raw = y1[((b * 64) + ch) * HW + gh * 56 + gw];
            v = fmaxf(st[FIN1 + ch] * raw + st[FIN1 + 64 + ch], 0.f);
        }
        ps[c][r][wc] = v;
    }
    __syncthreads();
    float accv[8];
    #pragma unroll
    for (int c = 0; c < 8; c++) accv[c] = 0.f;
    bool active = t < 224;
    if (active) {
        int lh = t / 56, lw = t % 56;
        float tsr[16];
        #pragma unroll
        for (int c = 0; c < 16; c++) tsr[c] = ts[c][t];
        float kr[49];
        #pragma unroll
        for (int k = 0; k < 49; k++) {
            const float4* swr = (const float4*)&sw[k][0];
            float4 u0 = swr[0], u1 = swr[1], u2 = swr[2], u3 = swr[3];
            float v = u0.x * tsr[0];
            v = fmaf(u0.y, tsr[1], v);  v = fmaf(u0.z, tsr[2], v);  v = fmaf(u0.w, tsr[3], v);
            v = fmaf(u1.x, tsr[4], v);  v = fmaf(u1.y, tsr[5], v);  v = fmaf(u1.z, tsr[6], v);
            v = fmaf(u1.w, tsr[7], v);  v = fmaf(u2.x, tsr[8], v);  v = fmaf(u2.y, tsr[9], v);
            v = fmaf(u2.z, tsr[10], v); v = fmaf(u2.w, tsr[11], v); v = fmaf(u3.x, tsr[12], v);
            v = fmaf(u3.y, tsr[13], v); v = fmaf(u3.z, tsr[14], v); v = fmaf(u3.w, tsr[15], v);
            kr[k] = v;
        }
        #pragma unroll
        for (int k = 0; k < 49; k++) {
            int ki = k / 7, kj = k % 7;
            float kv = kr[k];
            #pragma unroll
            for (int c = 0; c < 8; c++)
                accv[c] = fmaf(kv, ps[c][lh + ki][lw + kj], accv[c]);
        }
        int hw = h0 * 56 + t;
        uint4 o;
        o.x = f2bf(accv[0]) | ((unsigned)f2bf(accv[1]) << 16);
        o.y = f2bf(accv[2]) | ((unsigned)f2bf(accv[3]) << 16);
        o.z = f2bf(accv[4]) | ((unsigned)f2bf(accv[5]) << 16);
        o.w = f2bf(accv[6]) | ((unsigned)f2bf(accv[7]) << 16);
        *(uint4*)((char*)out2t + (size_t)(b * HW + hw) * 128 + (g * 16 + c0) * 2) = o;
    }
    int wave = t >> 6, lane = t & 63;
    #pragma unroll
    for (int c = 0; c < 8; c++) {
        float v = active ? accv[c] : 0.f;
        float s  = wave_sum(v);
        float s2 = wave_sum(v * v);
        if (lane == 0) { red[wave][c] = s; red[wave][8 + c] = s2; }
    }
    __syncthreads();
    if (t < 16) {
        float s = red[0][t] + red[1][t] + red[2][t] + red[3][t];
        int c = t & 7, isq = t >> 3;
        atomicAdd(&st[ACC2 + isq * 64 + g * 16 + c0 + c], s);
    }
}

// ---- K7: BN2+ReLU + conv 64->256 via MFMA + stats --------------------------
__global__ __launch_bounds__(256, 2) void k_bn2c3(const unsigned short* __restrict__ out2t,
        const unsigned short* __restrict__ w3bf, float* __restrict__ y3,
        float* __restrict__ st) {
    __shared__ unsigned short bs[64 * 64];   // 8KB, swizzled
    __shared__ float sa[64], sb[64];
    int t = threadIdx.x, pb = blockIdx.x;
    int b = pb / 49, hw0 = (pb % 49) * 64;
    int lane = t & 63, wv = t >> 6;
    int grp = lane >> 4, li = lane & 15;
    if (t < 64) sa[t] = st[FIN2 + t];
    else if (t < 128) { int c = t - 64; sb[c] = st[FIN2 + 64 + c]; }
    // A fragments: wave's 64-oc strip of w3bf[256][64]
    short8 a[8];
    #pragma unroll
    for (int m = 0; m < 4; m++)
        #pragma unroll
        for (int s = 0; s < 2; s++)
            a[m * 2 + s] = *(const short8*)(w3bf
                + (size_t)(wv * 64 + m * 16 + li) * 64 + s * 32 + grp * 8);
    __syncthreads();
    // stage B (64pix x 64ic) with BN2 affine + ReLU, swizzled ds_write
    #pragma unroll
    for (int i = 0; i < 2; i++) {
        int c = i * 256 + t, p = c >> 3, q = c & 7;
        uint4 v = *(const uint4*)((const char*)out2t + (size_t)(b * HW + hw0 + p) * 128 + q * 16);
        float4 fa0 = *(const float4*)&sa[q * 8];
        float4 fa1 = *(const float4*)&sa[q * 8 + 4];
        float4 fb0 = *(const float4*)&sb[q * 8];
        float4 fb1 = *(const float4*)&sb[q * 8 + 4];
        float e0 = fmaxf(fa0.x * bf2f(v.x & 0xFFFFu) + fb0.x, 0.f);
        float e1 = fmaxf(fa0.y * bf2f(v.x >> 16) + fb0.y, 0.f);
        float e2 = fmaxf(fa0.z * bf2f(v.y & 0xFFFFu) + fb0.z, 0.f);
        float e3 = fmaxf(fa0.w * bf2f(v.y >> 16) + fb0.w, 0.f);
        float e4 = fmaxf(fa1.x * bf2f(v.z & 0xFFFFu) + fb1.x, 0.f);
        float e5 = fmaxf(fa1.y * bf2f(v.z >> 16) + fb1.y, 0.f);
        float e6 = fmaxf(fa1.z * bf2f(v.w & 0xFFFFu) + fb1.z, 0.f);
        float e7 = fmaxf(fa1.w * bf2f(v.w >> 16) + fb1.w, 0.f);
        uint4 o;
        o.x = f2bf(e0) | ((unsigned)f2bf(e1) << 16);
        o.y = f2bf(e2) | ((unsigned)f2bf(e3) << 16);
        o.z = f2bf(e4) | ((unsigned)f2bf(e5) << 16);
        o.w = f2bf(e6) | ((unsigned)f2bf(e7) << 16);
        unsigned d = (unsigned)(p * 128 + q * 16) ^ (unsigned)((p & 7) << 4);
        *(uint4*)((char*)bs + d) = o;
    }
    __syncthreads();
    f32x4 acc[4][4];
    #pragma unroll
    for (int m = 0; m < 4; m++)
        #pragma unroll
        for (int n = 0; n < 4; n++) acc[m][n] = (f32x4){0.f, 0.f, 0.f, 0.f};
    #pragma unroll
    for (int s = 0; s < 2; s++)
        #pragma unroll
        for (int n = 0; n < 4; n++) {
            int row = n * 16 + li;
            unsigned o = (unsigned)(row * 128 + s * 64 + grp * 16) ^ (unsigned)((row & 7) << 4);
            short8 bf = *(const short8*)((const char*)bs + o);
            #pragma unroll
            for (int m = 0; m < 4; m++)
                acc[m][n] = __builtin_amdgcn_mfma_f32_16x16x32_bf16(a[m * 2 + s], bf, acc[m][n], 0, 0, 0);
        }
    #pragma unroll
    for (int m = 0; m < 4; m++) {
        #pragma unroll
        for (int n = 0; n < 4; n++)
            #pragma unroll
            for (int r = 0; r < 4; r++)
                y3[(size_t)(b * 256 + wv * 64 + m * 16 + grp * 4 + r) * HW
                   + hw0 + n * 16 + li] = acc[m][n][r];
        #pragma unroll
        for (int r = 0; r < 4; r++) {
            float s = acc[m][0][r] + acc[m][1][r] + acc[m][2][r] + acc[m][3][r];
            float q = acc[m][0][r] * acc[m][0][r] + acc[m][1][r] * acc[m][1][r]
                    + acc[m][2][r] * acc[m][2][r] + acc[m][3][r] * acc[m][3][r];
            #pragma unroll
            for (int off = 1; off <= 8; off <<= 1) {
                s += __shfl_xor(s, off, 64);
                q += __shfl_xor(q, off, 64);
            }
            if (li == 0) {
                int oc = wv * 64 + m * 16 + grp * 4 + r;
                atomicAdd(&st[ACC3 + oc], s);
                atomicAdd(&st[ACC3 + 256 + oc], q);
            }
        }
    }
}

// ---- K9: BN3 + residual + ReLU (float4) ------------------------------------
__global__ __launch_bounds__(256) void k_final(const float* __restrict__ y3,
        const float* __restrict__ x, float* __restrict__ out, const float* __restrict__ st) {
    int idx = blockIdx.x * 256 + threadIdx.x;
    if (idx < 1605632) {
        int c = (idx / 784) & 255;
        float a = st[FIN3 + c], bb = st[FIN3 + 256 + c];
        float4 v  = ((const float4*)y3)[idx];
        float4 xv = ((const float4*)x)[idx];
        float4 o;
        o.x = fmaxf(a * v.x + bb + xv.x, 0.f);
        o.y = fmaxf(a * v.y + bb + xv.y, 0.f);
        o.z = fmaxf(a * v.z + bb + xv.z, 0.f);
        o.w = fmaxf(a * v.w + bb + xv.w, 0.f);
        ((float4*)out)[idx] = o;
    }
}

extern "C" void kernel_launch(void* const* d_in, const int* in_sizes, int n_in,
                              void* d_out, int out_size, void* d_ws, size_t ws_size,
                              hipStream_t stream) {
    const float* x   = (const float*)d_in[0];
    const float* w1  = (const float*)d_in[1];
    const float* g1  = (const float*)d_in[2];
    const float* b1  = (const float*)d_in[3];
    const float* wr  = (const float*)d_in[4];
    const float* gr  = (const float*)d_in[5];
    const float* br  = (const float*)d_in[6];
    const float* wsp = (const float*)d_in[7];
    const float* g2  = (const float*)d_in[8];
    const float* b2  = (const float*)d_in[9];
    const float* w3  = (const float*)d_in[10];
    const float* g3  = (const float*)d_in[11];
    const float* b3  = (const float*)d_in[12];
    float* out = (float*)d_out;
    float* w   = (float*)d_ws;
    float* y1    = w + OFF_Y1;
    float* tr    = w + OFF_TR;
    unsigned short* w1bf  = (unsigned short*)(w + OFF_W1BF);
    unsigned short* w3bf  = (unsigned short*)(w + OFF_W3BF);
    unsigned short* xt    = (unsigned short*)(w + OFF_XT);
    unsigned short* out2t = (unsigned short*)(w + OFF_OUT2T);
    float* y3    = w + OFF_Y3;
    float* st    = w + OFF_ST;

    hipMemsetAsync(st, 0, 2048 * sizeof(float), stream);
    k_prep<<<128, 256, 0, stream>>>(w1, w3, w1bf, w3bf);
    k_tx<<<1568, 256, 0, stream>>>(x, xt);
    k_conv1<<<NBLK, 256, 0, stream>>>(xt, w1bf, y1, st);
    k_fin<<<1, 64, 0, stream>>>(st + ACC1, st + FIN1, g1, b1, 64);
    k_bn1_convr<<<NBLK, 256, 0, stream>>>(y1, wr, tr, st);
    k_fin<<<1, 64, 0, stream>>>(st + ACCR, st + FINR, gr, br, 16);
    k_invol<<<896, 256, 0, stream>>>(y1, tr, wsp, out2t, st);
    k_fin<<<1, 64, 0, stream>>>(st + ACC2, st + FIN2, g2, b2, 64);
    k_bn2c3<<<NBLK, 256, 0, stream>>>(out2t, w3bf, y3, st);
    k_fin<<<1, 256, 0, stream>>>(st + ACC3, st + FIN3, g3, b3, 256);
    k_final<<<6272, 256, 0, stream>>>(y3, x, out, st);
}